// Round 2
// baseline (3569.346 us; speedup 1.0000x reference)
//
#include <hip/hip_runtime.h>
#include <stdint.h>

// Problem constants (from reference)
#define B_    8
#define N_    20000
#define K_    12
#define F_    64
#define OUT_  128
#define D_    768            // K_*F_ flattened (s,f)
#define TM    32             // nodes per block (20000 = 625*32)
#define NTILES 625
#define KC    16             // k-chunk staged in LDS (fp32 W)

typedef __attribute__((ext_vector_type(4))) float f32x4;
typedef __attribute__((ext_vector_type(8))) short short8;

__device__ __forceinline__ ushort f2bf(float x) {
    union { float f; uint32_t u; } c; c.f = x;
    c.u += 0x7FFFu + ((c.u >> 16) & 1u);   // RNE
    return (ushort)(c.u >> 16);
}
__device__ __forceinline__ float bf2f(ushort h) {
    union { uint32_t u; float f; } c; c.u = ((uint32_t)h) << 16;
    return c.f;
}

__global__ __launch_bounds__(256) void paiconv_fp32_kernel(
    const float* __restrict__ x,      // [B,N,F]
    const int*   __restrict__ adj,    // [B,N,K]
    const float* __restrict__ adjw,   // [N,K,K]
    const float* __restrict__ W,      // [OUT,D] fp32
    const float* __restrict__ bias,   // [OUT]
    float*       __restrict__ out)    // [B,N,OUT]
{
    __shared__ ushort E[TM][D_];      // 49152 B: ELU'd features, bf16
    __shared__ float  Wl[OUT_][KC];   // 8192 B: fp32 W chunk

    const int tile = blockIdx.x % NTILES;
    const int b    = blockIdx.x / NTILES;
    const int tid  = threadIdx.x;

    // ---------- Phase 1: gather -> adjweight mix -> ELU -> LDS (bf16) ----------
    {
        const int nl = tid >> 3;            // node within tile (0..31)
        const int fb = (tid & 7) * 8;       // feature base (8 floats per thread)
        const int n  = tile * TM + nl;

        const int* ap = adj + ((size_t)b * N_ + n) * K_;
        float sp[K_][8];
        #pragma unroll
        for (int k = 0; k < K_; ++k) {
            const int id = ap[k];
            const float* xp = x + ((size_t)b * N_ + id) * F_ + fb;
            f32x4 v0 = *(const f32x4*)xp;
            f32x4 v1 = *(const f32x4*)(xp + 4);
            #pragma unroll
            for (int j = 0; j < 4; ++j) { sp[k][j] = v0[j]; sp[k][4 + j] = v1[j]; }
        }

        const float* wp = adjw + (size_t)n * (K_ * K_);
        #pragma unroll
        for (int s = 0; s < K_; ++s) {
            float acc1[8] = {0.f,0.f,0.f,0.f,0.f,0.f,0.f,0.f};
            #pragma unroll
            for (int k = 0; k < K_; ++k) {
                const float a = wp[k * K_ + s];
                #pragma unroll
                for (int j = 0; j < 8; ++j) acc1[j] = fmaf(sp[k][j], a, acc1[j]);
            }
            #pragma unroll
            for (int j = 0; j < 8; ++j) {
                float v = acc1[j];
                v = v > 0.f ? v : (__expf(v) - 1.f);   // ELU
                E[nl][s * F_ + fb + j] = f2bf(v);
            }
        }
    }
    __syncthreads();

    // ---------- Phase 2: [32 x 768] x [768 x 128] in plain fp32 VALU ----------
    const int nl = tid >> 3;             // row (node) this thread owns
    const int ob = (tid & 7) * 16;       // 16 consecutive output cols

    float acc[16];
    #pragma unroll
    for (int j = 0; j < 16; ++j) acc[j] = 0.f;

    const int wo = tid >> 1;             // W stage: row 0..127
    const int wh = (tid & 1) * 8;        // half of the 16-wide chunk

    for (int k0 = 0; k0 < D_; k0 += KC) {
        // stage fp32 W chunk [128][KC]
        {
            const float* wsrc = W + (size_t)wo * D_ + k0 + wh;
            f32x4 a0 = *(const f32x4*)wsrc;
            f32x4 a1 = *(const f32x4*)(wsrc + 4);
            *(f32x4*)&Wl[wo][wh]     = a0;
            *(f32x4*)&Wl[wo][wh + 4] = a1;
        }
        __syncthreads();

        #pragma unroll
        for (int k8 = 0; k8 < KC; k8 += 8) {
            short8 evv = *(const short8*)&E[nl][k0 + k8];
            float ev[8];
            #pragma unroll
            for (int i = 0; i < 8; ++i) ev[i] = bf2f((ushort)evv[i]);
            #pragma unroll
            for (int jj = 0; jj < 16; ++jj) {
                f32x4 w0 = *(const f32x4*)&Wl[ob + jj][k8];
                f32x4 w1 = *(const f32x4*)&Wl[ob + jj][k8 + 4];
                float a = acc[jj];
                a = fmaf(ev[0], w0[0], a);
                a = fmaf(ev[1], w0[1], a);
                a = fmaf(ev[2], w0[2], a);
                a = fmaf(ev[3], w0[3], a);
                a = fmaf(ev[4], w1[0], a);
                a = fmaf(ev[5], w1[1], a);
                a = fmaf(ev[6], w1[2], a);
                a = fmaf(ev[7], w1[3], a);
                acc[jj] = a;
            }
        }
        __syncthreads();
    }

    // ---------- Epilogue: bias + ELU + mask + store ----------
    const int n = tile * TM + nl;
    float* op = out + ((size_t)b * N_ + n) * OUT_ + ob;
    #pragma unroll
    for (int jj = 0; jj < 16; ++jj) {
        float v = acc[jj] + bias[ob + jj];
        v = v > 0.f ? v : (__expf(v) - 1.f);   // ELU
        if (n == N_ - 1) v = 0.f;              // zero-pad mask (last node, all batches)
        op[jj] = v;
    }
}

extern "C" void kernel_launch(void* const* d_in, const int* in_sizes, int n_in,
                              void* d_out, int out_size, void* d_ws, size_t ws_size,
                              hipStream_t stream) {
    const float* x    = (const float*)d_in[0];
    const int*   adj  = (const int*)d_in[1];
    // d_in[2] = kernal_weight: unused by the forward pass
    const float* adjw = (const float*)d_in[3];
    const float* W    = (const float*)d_in[4];
    const float* bias = (const float*)d_in[5];
    float* out = (float*)d_out;

    paiconv_fp32_kernel<<<B_ * NTILES, 256, 0, stream>>>(x, adj, adjw, W, bias, out);
}

// Round 6
// 398.540 us; speedup vs baseline: 8.9561x; 8.9561x over previous
//
#include <hip/hip_runtime.h>
#include <stdint.h>

// Problem constants (from reference)
#define B_    8
#define N_    20000
#define K_    12
#define F_    64
#define OUT_  128
#define D_    768            // K_*F_ flattened (s,f)
#define TM    32             // nodes per block (20000 = 625*32)
#define NTILES 625
#define LDE   776            // padded E row (bf16): 1552 B -> rows step 4 banks (2-way max, free)

typedef __attribute__((ext_vector_type(4))) float f32x4;
typedef __attribute__((ext_vector_type(8))) short short8;

__device__ __forceinline__ ushort f2bf(float x) {
    union { float f; uint32_t u; } c; c.f = x;
    c.u += 0x7FFFu + ((c.u >> 16) & 1u);   // RNE
    return (ushort)(c.u >> 16);
}

// Build a bf16x8 MFMA fragment from 8 consecutive fp32 values (16B-aligned).
__device__ __forceinline__ short8 ld_w8(const float* p) {
    f32x4 w0 = *(const f32x4*)p;
    f32x4 w1 = *(const f32x4*)(p + 4);
    union { short8 s8; ushort us[8]; } t;
    #pragma unroll
    for (int j = 0; j < 4; ++j) { t.us[j] = f2bf(w0[j]); t.us[4 + j] = f2bf(w1[j]); }
    return t.s8;
}

__global__ __launch_bounds__(256) void paiconv_mfma_kernel(
    const float* __restrict__ x,      // [B,N,F]
    const int*   __restrict__ adj,    // [B,N,K]
    const float* __restrict__ adjw,   // [N,K,K]
    const float* __restrict__ W,      // [OUT,D] fp32
    const float* __restrict__ bias,   // [OUT]
    float*       __restrict__ out)    // [B,N,OUT]
{
    __shared__ __align__(16) union SM {
        ushort e[TM * LDE];            // 49664 B: ELU'd features, bf16 (phases 1-2)
        float  c[TM][OUT_ + 1];        // 16516 B: fp32 C tile (post-MFMA, padded +1)
    } sm;

    const int tile = blockIdx.x % NTILES;
    const int b    = blockIdx.x / NTILES;
    const int tid  = threadIdx.x;

    // ---------- Phase 1 (VERIFIED in R2): gather -> mix -> ELU -> bf16 LDS ----------
    {
        const int nl = tid >> 3;            // node within tile (0..31)
        const int fb = (tid & 7) * 8;       // feature base (8 floats per thread)
        const int n  = tile * TM + nl;

        const int* ap = adj + ((size_t)b * N_ + n) * K_;
        float sp[K_][8];
        #pragma unroll
        for (int k = 0; k < K_; ++k) {
            const int id = ap[k];
            const float* xp = x + ((size_t)b * N_ + id) * F_ + fb;
            f32x4 v0 = *(const f32x4*)xp;
            f32x4 v1 = *(const f32x4*)(xp + 4);
            #pragma unroll
            for (int j = 0; j < 4; ++j) { sp[k][j] = v0[j]; sp[k][4 + j] = v1[j]; }
        }

        const float* wp = adjw + (size_t)n * (K_ * K_);
        #pragma unroll
        for (int s = 0; s < K_; ++s) {
            float acc1[8] = {0.f,0.f,0.f,0.f,0.f,0.f,0.f,0.f};
            #pragma unroll
            for (int k = 0; k < K_; ++k) {
                const float a = wp[k * K_ + s];
                #pragma unroll
                for (int j = 0; j < 8; ++j) acc1[j] = fmaf(sp[k][j], a, acc1[j]);
            }
            #pragma unroll
            for (int j = 0; j < 8; ++j) {
                float v = acc1[j];
                v = v > 0.f ? v : (__expf(v) - 1.f);   // ELU
                sm.e[nl * LDE + s * F_ + fb + j] = f2bf(v);
            }
        }
    }
    __syncthreads();

    // ---------- Phase 2: [32 x 768] x [768 x 128]^T via mfma_f32_16x16x32_bf16 ----------
    // W loaded fp32 straight from global (L2-resident), converted in-register.
    const int wave = tid >> 6;          // 0..3 -> 32 output cols each
    const int lane = tid & 63;
    const int r    = lane & 15;
    const int kg   = lane >> 4;         // k-octet group 0..3

    f32x4 acc[2][2];
    #pragma unroll
    for (int i = 0; i < 2; ++i)
        #pragma unroll
        for (int j = 0; j < 2; ++j)
            acc[i][j] = (f32x4){0.f, 0.f, 0.f, 0.f};

    const int colbase = wave * 32;
    const ushort* e0  = &sm.e[r * LDE + kg * 8];
    const ushort* e1  = &sm.e[(16 + r) * LDE + kg * 8];
    const float*  wf0 = W + (size_t)(colbase + r) * D_ + kg * 8;
    const float*  wf1 = W + (size_t)(colbase + 16 + r) * D_ + kg * 8;

    for (int kb = 0; kb < D_; kb += 32) {
        short8 a0 = *(const short8*)(e0 + kb);
        short8 a1 = *(const short8*)(e1 + kb);
        short8 b0 = ld_w8(wf0 + kb);
        short8 b1 = ld_w8(wf1 + kb);
        acc[0][0] = __builtin_amdgcn_mfma_f32_16x16x32_bf16(a0, b0, acc[0][0], 0, 0, 0);
        acc[0][1] = __builtin_amdgcn_mfma_f32_16x16x32_bf16(a0, b1, acc[0][1], 0, 0, 0);
        acc[1][0] = __builtin_amdgcn_mfma_f32_16x16x32_bf16(a1, b0, acc[1][0], 0, 0, 0);
        acc[1][1] = __builtin_amdgcn_mfma_f32_16x16x32_bf16(a1, b1, acc[1][1], 0, 0, 0);
    }

    // ---------- C -> LDS via C/D layout (col=lane&15, row=4*(lane>>4)+j) ----------
    __syncthreads();   // all E reads done before overwriting the union
    #pragma unroll
    for (int mt = 0; mt < 2; ++mt)
        #pragma unroll
        for (int nt = 0; nt < 2; ++nt)
            #pragma unroll
            for (int j = 0; j < 4; ++j)
                sm.c[mt * 16 + kg * 4 + j][colbase + nt * 16 + r] = acc[mt][nt][j];
    __syncthreads();

    // ---------- Epilogue (VERIFIED in R2): bias + ELU + mask + coalesced store ----------
    {
        const int nl = tid >> 3;
        const int ob = (tid & 7) * 16;
        const int n  = tile * TM + nl;
        float* op = out + ((size_t)b * N_ + n) * OUT_ + ob;
        float vv[16];
        #pragma unroll
        for (int jj = 0; jj < 16; ++jj) {
            float v = sm.c[nl][ob + jj] + bias[ob + jj];
            v = v > 0.f ? v : (__expf(v) - 1.f);   // ELU
            if (n == N_ - 1) v = 0.f;              // zero-pad mask (last node, all batches)
            vv[jj] = v;
        }
        #pragma unroll
        for (int q = 0; q < 4; ++q) {
            f32x4 o4 = { vv[q*4+0], vv[q*4+1], vv[q*4+2], vv[q*4+3] };
            *(f32x4*)(op + q * 4) = o4;
        }
    }
}

extern "C" void kernel_launch(void* const* d_in, const int* in_sizes, int n_in,
                              void* d_out, int out_size, void* d_ws, size_t ws_size,
                              hipStream_t stream) {
    const float* x    = (const float*)d_in[0];
    const int*   adj  = (const int*)d_in[1];
    // d_in[2] = kernal_weight: unused by the forward pass
    const float* adjw = (const float*)d_in[3];
    const float* W    = (const float*)d_in[4];
    const float* bias = (const float*)d_in[5];
    float* out = (float*)d_out;

    paiconv_mfma_kernel<<<B_ * NTILES, 256, 0, stream>>>(x, adj, adjw, W, bias, out);
}